// Round 18
// baseline (259.176 us; speedup 1.0000x reference)
//
#include <hip/hip_runtime.h>
#include <hip/hip_bf16.h>

#define L 4096
#define NB 8
#define C 192
#define CQK 24
#define DP 32      // padded qk head dim
#define QBLK 64
#define KBLK 64
#define NTT (L / 2 / KBLK)   // 32 tiles per split half
// proj_mfma tile
#define BN 64      // l-columns per block
#define XS_W 200   // padded row width of Xs[l][c]
#define LOG2E 1.4426950408889634f

typedef _Float16 half_t;
typedef __fp16 fp16x2 __attribute__((ext_vector_type(2)));
typedef __fp16 fp16x4 __attribute__((ext_vector_type(4)));
typedef _Float16 half8 __attribute__((ext_vector_type(8)));
typedef float f32x4 __attribute__((ext_vector_type(4)));

// ---------------- MFMA projection kernel (unchanged) ----------------

__global__ __launch_bounds__(256, 2) void proj_mfma(const float* __restrict__ x,
                                                    const float* __restrict__ Wq,
                                                    const float* __restrict__ Wk,
                                                    const float* __restrict__ Wv,
                                                    half_t* __restrict__ Qh,
                                                    half_t* __restrict__ Kh,
                                                    half_t* __restrict__ Vh) {
  __shared__ half_t Xs[BN][XS_W];  // X^T tile [l][c]
  __shared__ half_t Qt[BN][DP];    // Q staging [l][o]
  __shared__ half_t Kt[BN][DP];    // K staging

  int tid = threadIdx.x;
  int lane = tid & 63;
  int wave = tid >> 6;
  int li = lane & 15;
  int g = lane >> 4;

  int blk = blockIdx.x;
  int n = blk >> 6;
  int l0 = (blk & 63) * BN;

  const float* xbase = x + (size_t)n * C * L + l0;
#pragma unroll
  for (int it = 0; it < 12; ++it) {
    int fid = it * 256 + tid;
    int l4 = fid & 15;
    int c = fid >> 4;
    f32x4 v = *reinterpret_cast<const f32x4*>(xbase + (size_t)c * L + l4 * 4);
#pragma unroll
    for (int j = 0; j < 4; ++j) Xs[l4 * 4 + j][c] = (half_t)v[j];
  }
  __syncthreads();

  const float* rowp[4];
  bool rvalid[4];
#pragma unroll
  for (int mt = 0; mt < 4; ++mt) {
    int row = wave * 64 + mt * 16 + li;
    const float* p;
    bool v = true;
    if (row < 32) {
      v = row < CQK;
      p = Wq + (size_t)(v ? row : 0) * C;
    } else if (row < 64) {
      v = (row - 32) < CQK;
      p = Wk + (size_t)(v ? row - 32 : 0) * C;
    } else {
      p = Wv + (size_t)(row - 64) * C;
    }
    rowp[mt] = p;
    rvalid[mt] = v;
  }

  f32x4 acc[4][4];
#pragma unroll
  for (int mt = 0; mt < 4; ++mt)
#pragma unroll
    for (int nt = 0; nt < 4; ++nt) acc[mt][nt] = {0.f, 0.f, 0.f, 0.f};

  half8 az;
#pragma unroll
  for (int j = 0; j < 8; ++j) az[j] = (half_t)0.f;

#pragma unroll
  for (int kk = 0; kk < 6; ++kk) {
    half8 af[4];
#pragma unroll
    for (int mt = 0; mt < 4; ++mt) {
      const float* p = rowp[mt] + kk * 32 + g * 8;
      f32x4 w0 = *reinterpret_cast<const f32x4*>(p);
      f32x4 w1 = *reinterpret_cast<const f32x4*>(p + 4);
      half8 a;
#pragma unroll
      for (int j = 0; j < 4; ++j) {
        a[j] = (half_t)w0[j];
        a[4 + j] = (half_t)w1[j];
      }
      af[mt] = rvalid[mt] ? a : az;
    }
#pragma unroll
    for (int nt = 0; nt < 4; ++nt) {
      half8 b = *reinterpret_cast<const half8*>(&Xs[nt * 16 + li][kk * 32 + g * 8]);
#pragma unroll
      for (int mt = 0; mt < 4; ++mt)
        acc[mt][nt] = __builtin_amdgcn_mfma_f32_16x16x32_f16(af[mt], b, acc[mt][nt], 0, 0, 0);
    }
  }

  if (wave >= 1) {
#pragma unroll
    for (int mt = 0; mt < 4; ++mt)
#pragma unroll
      for (int nt = 0; nt < 4; ++nt)
#pragma unroll
        for (int r = 0; r < 4; ++r) {
          int c = (wave - 1) * 64 + mt * 16 + 4 * g + r;
          int l = nt * 16 + li;
          Vh[((size_t)n * C + c) * L + l0 + l] = (half_t)acc[mt][nt][r];
        }
  } else {
#pragma unroll
    for (int mt = 0; mt < 4; ++mt)
#pragma unroll
      for (int nt = 0; nt < 4; ++nt)
#pragma unroll
        for (int r = 0; r < 4; ++r) {
          int o = (mt & 1) * 16 + 4 * g + r;
          int l = nt * 16 + li;
          if (mt < 2) Qt[l][o] = (half_t)(acc[mt][nt][r] * LOG2E);
          else        Kt[l][o] = (half_t)acc[mt][nt][r];
        }
  }
  __syncthreads();

  if (tid < 128) {
    int which = tid >> 6;
    int l = tid & 63;
    const half8* src = reinterpret_cast<const half8*>(which ? &Kt[l][0] : &Qt[l][0]);
    half_t* dstp = (which ? Kh : Qh) + ((size_t)n * L + l0 + l) * DP;
    half8* dst = reinterpret_cast<half8*>(dstp);
#pragma unroll
    for (int i = 0; i < 4; ++i) dst[i] = src[i];
  }
}

// ---------------- flash attention, split-KV (single instantiation) ----------------
// Round-18: rule-#19 fix. r15/16/17 co-compiled attn<true>+attn<false> in one
// TU -> shared-regalloc perturbation -> nonsense VGPR (64/84) + 100+ MB spill.
// This round: ONE non-templated kernel = r12's exact double-buffered pipeline
// (the known-clean 104-VGPR codegen) + the sign-fixed partial epilogue.
// Grid (NB, 64, 2), launch_bounds(256,3): ~110 VGPR -> HW fits 4 blocks/CU.

struct SMemA {
  half_t P[2][QBLK][KBLK];  // swizzled: byte ^= (row&7)<<4
  float rs[2][QBLK];        // per-row rescale, permuted [li*4+wave]
  float Ls[QBLK];           // row sums, permuted
  float Cs[QBLK];           // row coffs, permuted
};

__global__ __launch_bounds__(256, 3) void attn_split(
    const half_t* __restrict__ Qh, const half_t* __restrict__ Kh,
    const half_t* __restrict__ Vh,
    half_t* __restrict__ Op, float* __restrict__ Lp, float* __restrict__ Cp) {
  __shared__ SMemA sm;

  const int tid = threadIdx.x;
  const int wave = tid >> 6;
  const int lane = tid & 63;
  const int li = lane & 15;
  const int g = lane >> 4;
  const int n = blockIdx.x;
  const int q0 = blockIdx.y * QBLK;
  const int z = blockIdx.z;
  const int kv0 = z * (L / 2);
  const int c0 = wave * 48;
  const int swz = (li & 7) << 4;

  const half8 qfrag = *reinterpret_cast<const half8*>(
      Qh + ((size_t)(n * L + q0 + wave * 16 + li)) * DP + g * 8);

  const char* kptr = (const char*)(Kh + (size_t)(n * L + kv0) * DP) +
                     ((size_t)li * DP + g * 8) * 2;
  const char* vb[3];
  vb[0] = (const char*)(Vh + (size_t)n * C * L + kv0) +
          ((size_t)(c0 + li) * L + g * 8) * 2;
  vb[1] = vb[0] + (size_t)16 * L * 2;
  vb[2] = vb[0] + (size_t)32 * L * 2;

  f32x4 acc[3][4];
#pragma unroll
  for (int ct = 0; ct < 3; ++ct)
#pragma unroll
    for (int qt = 0; qt < 4; ++qt) acc[ct][qt] = {0.f, 0.f, 0.f, 0.f};

  float Lrow = 0.f;    // per-lane partial row sum (q = wave*16+li)
  float coff = -28.f;  // per-row offset (log2 units), in MFMA C-operand

  half8 kA[4], vA[6], kB[4], vB[6];

  // softmax + P/rs write for parity `par` (r12's exact known-good codegen)
  auto sm_write = [&](const f32x4(&s)[4], int par) {
    float p[4][4];
    float mx = -1.0e30f;
#pragma unroll
    for (int b = 0; b < 4; ++b) {
      mx = fmaxf(mx, fmaxf(fmaxf(s[b][0], s[b][1]), fmaxf(s[b][2], s[b][3])));
#pragma unroll
      for (int r = 0; r < 4; ++r) p[b][r] = __builtin_amdgcn_exp2f(s[b][r]);
    }
    float sc = 1.0f;
    if (__any((int)(mx > 15.f))) {  // rare overflow path
      float m2 = fmaxf(mx, __shfl_xor(mx, 16));
      m2 = fmaxf(m2, __shfl_xor(m2, 32));
      if (m2 > 15.f) {
        sc = __builtin_amdgcn_exp2f(-m2);
        Lrow *= sc;
        coff -= m2;
#pragma unroll
        for (int b = 0; b < 4; ++b)
#pragma unroll
          for (int r = 0; r < 4; ++r)
            p[b][r] = __builtin_amdgcn_exp2f(s[b][r] - m2);
      }
    }
#pragma unroll
    for (int b = 0; b < 4; ++b)
#pragma unroll
      for (int r = 0; r < 4; ++r) Lrow += p[b][r];

    char* prow = (char*)&sm.P[par][wave * 16 + li][0];
#pragma unroll
    for (int b = 0; b < 4; ++b) {
      fp16x2 lo = __builtin_amdgcn_cvt_pkrtz(p[b][0], p[b][1]);
      fp16x2 hi = __builtin_amdgcn_cvt_pkrtz(p[b][2], p[b][3]);
      fp16x4 h = __builtin_shufflevector(lo, hi, 0, 1, 2, 3);
      *reinterpret_cast<fp16x4*>(prow + ((b * 32 + 8 * g) ^ swz)) = h;
    }
    if (lane < 16) sm.rs[par][li * 4 + wave] = sc;
  };

  auto apply_rescale = [&](int par) {
    f32x4 f = *reinterpret_cast<const f32x4*>(&sm.rs[par][li * 4]);
    bool an = (f[0] != 1.f) | (f[1] != 1.f) | (f[2] != 1.f) | (f[3] != 1.f);
    if (__any((int)an)) {
#pragma unroll
      for (int ct = 0; ct < 3; ++ct)
#pragma unroll
        for (int qt = 0; qt < 4; ++qt) acc[ct][qt] *= f[qt];
    }
  };

  auto pv = [&](const half8(&vp)[6], int par) {
#pragma unroll
    for (int ch = 0; ch < 2; ++ch)
#pragma unroll
      for (int qt = 0; qt < 4; ++qt) {
        const char* prow = (const char*)&sm.P[par][qt * 16 + li][0];
        half8 pfrag = *reinterpret_cast<const half8*>(
            prow + ((ch * 64 + 16 * g) ^ swz));
#pragma unroll
        for (int ct = 0; ct < 3; ++ct)
          acc[ct][qt] = __builtin_amdgcn_mfma_f32_16x16x32_f16(
              vp[ct * 2 + ch], pfrag, acc[ct][qt], 0, 0, 0);
      }
  };

  // prologue: K(0)->kA, K(1)->kB, V(0)->vA; QK(0); softmax(0)
#pragma unroll
  for (int b = 0; b < 4; ++b)
    kA[b] = *reinterpret_cast<const half8*>(kptr + b * 1024);
  kptr += KBLK * DP * 2;
#pragma unroll
  for (int b = 0; b < 4; ++b)
    kB[b] = *reinterpret_cast<const half8*>(kptr + b * 1024);
  kptr += KBLK * DP * 2;
#pragma unroll
  for (int ct = 0; ct < 3; ++ct) {
    vA[ct * 2 + 0] = *reinterpret_cast<const half8*>(vb[ct]);
    vA[ct * 2 + 1] = *reinterpret_cast<const half8*>(vb[ct] + 64);
    vb[ct] += KBLK * 2;
  }
  {
    f32x4 cvec = {coff, coff, coff, coff};
    f32x4 s[4];
#pragma unroll
    for (int b = 0; b < 4; ++b)
      s[b] = __builtin_amdgcn_mfma_f32_16x16x32_f16(kA[b], qfrag, cvec, 0, 0, 0);
    sm_write(s, 0);
  }
  asm volatile("s_waitcnt lgkmcnt(0)\n\ts_barrier" ::: "memory");

  // phase t: QK(t+1) from kq; rescale(t)+PV(t); loads K(t+2)->kd, V(t+1)->vd
  auto phase = [&](const half8(&kq)[4], const half8(&vp)[6], half8(&kd)[4],
                   half8(&vd)[6], int par, bool doK) {
    if (doK) {
#pragma unroll
      for (int b = 0; b < 4; ++b)
        kd[b] = *reinterpret_cast<const half8*>(kptr + b * 1024);
      kptr += KBLK * DP * 2;
    }
#pragma unroll
    for (int ct = 0; ct < 3; ++ct) {
      vd[ct * 2 + 0] = *reinterpret_cast<const half8*>(vb[ct]);
      vd[ct * 2 + 1] = *reinterpret_cast<const half8*>(vb[ct] + 64);
      vb[ct] += KBLK * 2;
    }

    f32x4 cvec = {coff, coff, coff, coff};
    f32x4 s[4];
#pragma unroll
    for (int b = 0; b < 4; ++b)
      s[b] = __builtin_amdgcn_mfma_f32_16x16x32_f16(kq[b], qfrag, cvec, 0, 0, 0);

    apply_rescale(par);
    pv(vp, par);

    sm_write(s, par ^ 1);
    asm volatile("s_waitcnt lgkmcnt(0)\n\ts_barrier" ::: "memory");
  };

  for (int t = 0; t < NTT - 2; t += 2) {
    phase(kB, vA, kA, vB, 0, true);
    phase(kA, vB, kB, vA, 1, true);
  }
  phase(kB, vA, kA, vB, 0, false);  // t = NTT-2

  // epilogue tile NTT-1 (par=1, NTT even)
  apply_rescale(1);
  pv(vB, 1);

  // row sums + coffs -> LDS (permuted)
  float sum = Lrow;
  sum += __shfl_xor(sum, 16);
  sum += __shfl_xor(sum, 32);
  if (lane < 16) {
    sm.Ls[li * 4 + wave] = sum;
    sm.Cs[li * 4 + wave] = coff;
  }
  __syncthreads();

  f32x4 Lv = *reinterpret_cast<const f32x4*>(&sm.Ls[li * 4]);
  f32x4 Cv = *reinterpret_cast<const f32x4*>(&sm.Cs[li * 4]);
  float osc[4];
  int eb[4];
#pragma unroll
  for (int qt = 0; qt < 4; ++qt) {
    eb[qt] = (int)(__float_as_uint(Lv[qt]) >> 23) - 127;        // floor(log2 L)
    osc[qt] = __uint_as_float((uint32_t)(127 - eb[qt]) << 23);  // 2^-e
  }
  half_t* ob = Op + (size_t)(n * 2 + z) * C * L;
#pragma unroll
  for (int ct = 0; ct < 3; ++ct)
#pragma unroll
    for (int qt = 0; qt < 4; ++qt)
#pragma unroll
      for (int r = 0; r < 4; ++r)
        ob[((size_t)(c0 + ct * 16 + 4 * g + r)) * L + q0 + qt * 16 + li] =
            (half_t)(acc[ct][qt][r] * osc[qt]);
  if (lane < 16) {
    size_t ridx = (size_t)(n * 2 + z) * L + q0 + wave * 16 + li;
    Lp[ridx] = Lv[wave] * osc[wave];
    // merge weight f = 2^(e - coff): acc_true = acc*2^-coff, O' = acc*2^-e
    Cp[ridx] = (float)eb[wave] - Cv[wave];
  }
}

// ---------------- split merge ----------------

__global__ __launch_bounds__(256) void merge_split(
    const half_t* __restrict__ Op, const float* __restrict__ Lp,
    const float* __restrict__ Cp, float* __restrict__ out) {
  int n = blockIdx.x;
  int l = blockIdx.y * 64 + (threadIdx.x & 63);
  int cs = threadIdx.x >> 6;

  size_t ra = (size_t)(n * 2 + 0) * L + l;
  size_t rb = (size_t)(n * 2 + 1) * L + l;
  float La = Lp[ra], Ca = Cp[ra];
  float Lb = Lp[rb], Cb = Cp[rb];
  float cm = fmaxf(Ca, Cb);
  float fa = exp2f(Ca - cm), fb = exp2f(Cb - cm);
  float D = La * fa + Lb * fb;
  float wa = fa / D, wb = fb / D;

  const half_t* Oa = Op + (size_t)(n * 2 + 0) * C * L;
  const half_t* Ob = Op + (size_t)(n * 2 + 1) * C * L;
  float* ob = out + (size_t)n * C * L;
#pragma unroll
  for (int j = 0; j < 48; ++j) {
    size_t idx = (size_t)(cs * 48 + j) * L + l;
    ob[idx] = wa * (float)Oa[idx] + wb * (float)Ob[idx];
  }
}

// ---------------- launcher ----------------

extern "C" void kernel_launch(void* const* d_in, const int* in_sizes, int n_in,
                              void* d_out, int out_size, void* d_ws, size_t ws_size,
                              hipStream_t stream) {
  (void)in_sizes; (void)n_in; (void)out_size; (void)ws_size;
  const float* x = (const float*)d_in[0];
  const float* Wq = (const float*)d_in[1];
  const float* Wk = (const float*)d_in[2];
  const float* Wv = (const float*)d_in[3];
  float* out = (float*)d_out;

  half_t* Qh = (half_t*)d_ws;                          // [NB][L][DP] f16
  half_t* Kh = Qh + (size_t)NB * L * DP;               // [NB][L][DP] f16
  half_t* Vh = Kh + (size_t)NB * L * DP;               // [NB][C][L]  f16
  half_t* Op = Vh + (size_t)NB * C * L;                // [NB][2][C][L] f16
  float* Lp = (float*)(Op + (size_t)NB * 2 * C * L);   // [NB][2][L] f32
  float* Cp = Lp + (size_t)NB * 2 * L;                 // [NB][2][L] f32

  hipLaunchKernelGGL(proj_mfma, dim3(NB * (L / BN)), dim3(256), 0, stream,
                     x, Wq, Wk, Wv, Qh, Kh, Vh);
  hipLaunchKernelGGL(attn_split, dim3(NB, L / QBLK, 2), dim3(256), 0, stream,
                     Qh, Kh, Vh, Op, Lp, Cp);
  hipLaunchKernelGGL(merge_split, dim3(NB, L / 64), dim3(256), 0, stream,
                     Op, Lp, Cp, out);
}

// Round 19
// 150.488 us; speedup vs baseline: 1.7222x; 1.7222x over previous
//
#include <hip/hip_runtime.h>
#include <hip/hip_bf16.h>

#define L 4096
#define NB 8
#define C 192
#define CQK 24
#define DP 32      // padded qk head dim
#define QBLK 64
#define KBLK 64
#define NTT (L / 2 / KBLK)   // 32 tiles per split half
// proj_mfma tile
#define BN 64      // l-columns per block
#define XS_W 200   // padded row width of Xs[l][c]
#define LOG2E 1.4426950408889634f

typedef _Float16 half_t;
typedef __fp16 fp16x2 __attribute__((ext_vector_type(2)));
typedef __fp16 fp16x4 __attribute__((ext_vector_type(4)));
typedef _Float16 half8 __attribute__((ext_vector_type(8)));
typedef float f32x4 __attribute__((ext_vector_type(4)));

// ---------------- MFMA projection kernel (unchanged) ----------------

__global__ __launch_bounds__(256, 2) void proj_mfma(const float* __restrict__ x,
                                                    const float* __restrict__ Wq,
                                                    const float* __restrict__ Wk,
                                                    const float* __restrict__ Wv,
                                                    half_t* __restrict__ Qh,
                                                    half_t* __restrict__ Kh,
                                                    half_t* __restrict__ Vh) {
  __shared__ half_t Xs[BN][XS_W];  // X^T tile [l][c]
  __shared__ half_t Qt[BN][DP];    // Q staging [l][o]
  __shared__ half_t Kt[BN][DP];    // K staging

  int tid = threadIdx.x;
  int lane = tid & 63;
  int wave = tid >> 6;
  int li = lane & 15;
  int g = lane >> 4;

  int blk = blockIdx.x;
  int n = blk >> 6;
  int l0 = (blk & 63) * BN;

  const float* xbase = x + (size_t)n * C * L + l0;
#pragma unroll
  for (int it = 0; it < 12; ++it) {
    int fid = it * 256 + tid;
    int l4 = fid & 15;
    int c = fid >> 4;
    f32x4 v = *reinterpret_cast<const f32x4*>(xbase + (size_t)c * L + l4 * 4);
#pragma unroll
    for (int j = 0; j < 4; ++j) Xs[l4 * 4 + j][c] = (half_t)v[j];
  }
  __syncthreads();

  const float* rowp[4];
  bool rvalid[4];
#pragma unroll
  for (int mt = 0; mt < 4; ++mt) {
    int row = wave * 64 + mt * 16 + li;
    const float* p;
    bool v = true;
    if (row < 32) {
      v = row < CQK;
      p = Wq + (size_t)(v ? row : 0) * C;
    } else if (row < 64) {
      v = (row - 32) < CQK;
      p = Wk + (size_t)(v ? row - 32 : 0) * C;
    } else {
      p = Wv + (size_t)(row - 64) * C;
    }
    rowp[mt] = p;
    rvalid[mt] = v;
  }

  f32x4 acc[4][4];
#pragma unroll
  for (int mt = 0; mt < 4; ++mt)
#pragma unroll
    for (int nt = 0; nt < 4; ++nt) acc[mt][nt] = {0.f, 0.f, 0.f, 0.f};

  half8 az;
#pragma unroll
  for (int j = 0; j < 8; ++j) az[j] = (half_t)0.f;

#pragma unroll
  for (int kk = 0; kk < 6; ++kk) {
    half8 af[4];
#pragma unroll
    for (int mt = 0; mt < 4; ++mt) {
      const float* p = rowp[mt] + kk * 32 + g * 8;
      f32x4 w0 = *reinterpret_cast<const f32x4*>(p);
      f32x4 w1 = *reinterpret_cast<const f32x4*>(p + 4);
      half8 a;
#pragma unroll
      for (int j = 0; j < 4; ++j) {
        a[j] = (half_t)w0[j];
        a[4 + j] = (half_t)w1[j];
      }
      af[mt] = rvalid[mt] ? a : az;
    }
#pragma unroll
    for (int nt = 0; nt < 4; ++nt) {
      half8 b = *reinterpret_cast<const half8*>(&Xs[nt * 16 + li][kk * 32 + g * 8]);
#pragma unroll
      for (int mt = 0; mt < 4; ++mt)
        acc[mt][nt] = __builtin_amdgcn_mfma_f32_16x16x32_f16(af[mt], b, acc[mt][nt], 0, 0, 0);
    }
  }

  if (wave >= 1) {
#pragma unroll
    for (int mt = 0; mt < 4; ++mt)
#pragma unroll
      for (int nt = 0; nt < 4; ++nt)
#pragma unroll
        for (int r = 0; r < 4; ++r) {
          int c = (wave - 1) * 64 + mt * 16 + 4 * g + r;
          int l = nt * 16 + li;
          Vh[((size_t)n * C + c) * L + l0 + l] = (half_t)acc[mt][nt][r];
        }
  } else {
#pragma unroll
    for (int mt = 0; mt < 4; ++mt)
#pragma unroll
      for (int nt = 0; nt < 4; ++nt)
#pragma unroll
        for (int r = 0; r < 4; ++r) {
          int o = (mt & 1) * 16 + 4 * g + r;
          int l = nt * 16 + li;
          if (mt < 2) Qt[l][o] = (half_t)(acc[mt][nt][r] * LOG2E);
          else        Kt[l][o] = (half_t)acc[mt][nt][r];
        }
  }
  __syncthreads();

  if (tid < 128) {
    int which = tid >> 6;
    int l = tid & 63;
    const half8* src = reinterpret_cast<const half8*>(which ? &Kt[l][0] : &Qt[l][0]);
    half_t* dstp = (which ? Kh : Qh) + ((size_t)n * L + l0 + l) * DP;
    half8* dst = reinterpret_cast<half8*>(dstp);
#pragma unroll
    for (int i = 0; i < 4; ++i) dst[i] = src[i];
  }
}

// ---------------- flash attention, split-KV ----------------
// Round-19: launch_bounds min-waves isolated as the spill trigger:
// (256,2)->104 VGPR clean; (256,3)->84+spill; (256,4)->64+1.7GB spill.
// The allocator can't fit acc AGPRs + pipeline VGPRs under a >=3-waves/EU
// budget and spills instead of relaxing. Fix: declare (256,2) (known-clean)
// and let HW occupancy follow ACTUAL allocation (~152 unified regs -> 3
// waves/SIMD -> 3 blocks/CU from the 1024-block split grid). Body = r12's
// double-buffered pipeline verbatim + sign-fixed partial epilogue.

struct SMemA {
  half_t P[2][QBLK][KBLK];  // swizzled: byte ^= (row&7)<<4
  float rs[2][QBLK];        // per-row rescale, permuted [li*4+wave]
  float Ls[QBLK];           // row sums, permuted
  float Cs[QBLK];           // row coffs, permuted
};

__global__ __launch_bounds__(256, 2) void attn_split(
    const half_t* __restrict__ Qh, const half_t* __restrict__ Kh,
    const half_t* __restrict__ Vh,
    half_t* __restrict__ Op, float* __restrict__ Lp, float* __restrict__ Cp) {
  __shared__ SMemA sm;

  const int tid = threadIdx.x;
  const int wave = tid >> 6;
  const int lane = tid & 63;
  const int li = lane & 15;
  const int g = lane >> 4;
  const int n = blockIdx.x;
  const int q0 = blockIdx.y * QBLK;
  const int z = blockIdx.z;
  const int kv0 = z * (L / 2);
  const int c0 = wave * 48;
  const int swz = (li & 7) << 4;

  const half8 qfrag = *reinterpret_cast<const half8*>(
      Qh + ((size_t)(n * L + q0 + wave * 16 + li)) * DP + g * 8);

  const char* kptr = (const char*)(Kh + (size_t)(n * L + kv0) * DP) +
                     ((size_t)li * DP + g * 8) * 2;
  const char* vb[3];
  vb[0] = (const char*)(Vh + (size_t)n * C * L + kv0) +
          ((size_t)(c0 + li) * L + g * 8) * 2;
  vb[1] = vb[0] + (size_t)16 * L * 2;
  vb[2] = vb[0] + (size_t)32 * L * 2;

  f32x4 acc[3][4];
#pragma unroll
  for (int ct = 0; ct < 3; ++ct)
#pragma unroll
    for (int qt = 0; qt < 4; ++qt) acc[ct][qt] = {0.f, 0.f, 0.f, 0.f};

  float Lrow = 0.f;    // per-lane partial row sum (q = wave*16+li)
  float coff = -28.f;  // per-row offset (log2 units), in MFMA C-operand

  half8 kA[4], vA[6], kB[4], vB[6];

  // softmax + P/rs write for parity `par` (r12's exact known-good codegen)
  auto sm_write = [&](const f32x4(&s)[4], int par) {
    float p[4][4];
    float mx = -1.0e30f;
#pragma unroll
    for (int b = 0; b < 4; ++b) {
      mx = fmaxf(mx, fmaxf(fmaxf(s[b][0], s[b][1]), fmaxf(s[b][2], s[b][3])));
#pragma unroll
      for (int r = 0; r < 4; ++r) p[b][r] = __builtin_amdgcn_exp2f(s[b][r]);
    }
    float sc = 1.0f;
    if (__any((int)(mx > 15.f))) {  // rare overflow path
      float m2 = fmaxf(mx, __shfl_xor(mx, 16));
      m2 = fmaxf(m2, __shfl_xor(m2, 32));
      if (m2 > 15.f) {
        sc = __builtin_amdgcn_exp2f(-m2);
        Lrow *= sc;
        coff -= m2;
#pragma unroll
        for (int b = 0; b < 4; ++b)
#pragma unroll
          for (int r = 0; r < 4; ++r)
            p[b][r] = __builtin_amdgcn_exp2f(s[b][r] - m2);
      }
    }
#pragma unroll
    for (int b = 0; b < 4; ++b)
#pragma unroll
      for (int r = 0; r < 4; ++r) Lrow += p[b][r];

    char* prow = (char*)&sm.P[par][wave * 16 + li][0];
#pragma unroll
    for (int b = 0; b < 4; ++b) {
      fp16x2 lo = __builtin_amdgcn_cvt_pkrtz(p[b][0], p[b][1]);
      fp16x2 hi = __builtin_amdgcn_cvt_pkrtz(p[b][2], p[b][3]);
      fp16x4 h = __builtin_shufflevector(lo, hi, 0, 1, 2, 3);
      *reinterpret_cast<fp16x4*>(prow + ((b * 32 + 8 * g) ^ swz)) = h;
    }
    if (lane < 16) sm.rs[par][li * 4 + wave] = sc;
  };

  auto apply_rescale = [&](int par) {
    f32x4 f = *reinterpret_cast<const f32x4*>(&sm.rs[par][li * 4]);
    bool an = (f[0] != 1.f) | (f[1] != 1.f) | (f[2] != 1.f) | (f[3] != 1.f);
    if (__any((int)an)) {
#pragma unroll
      for (int ct = 0; ct < 3; ++ct)
#pragma unroll
        for (int qt = 0; qt < 4; ++qt) acc[ct][qt] *= f[qt];
    }
  };

  auto pv = [&](const half8(&vp)[6], int par) {
#pragma unroll
    for (int ch = 0; ch < 2; ++ch)
#pragma unroll
      for (int qt = 0; qt < 4; ++qt) {
        const char* prow = (const char*)&sm.P[par][qt * 16 + li][0];
        half8 pfrag = *reinterpret_cast<const half8*>(
            prow + ((ch * 64 + 16 * g) ^ swz));
#pragma unroll
        for (int ct = 0; ct < 3; ++ct)
          acc[ct][qt] = __builtin_amdgcn_mfma_f32_16x16x32_f16(
              vp[ct * 2 + ch], pfrag, acc[ct][qt], 0, 0, 0);
      }
  };

  // prologue: K(0)->kA, K(1)->kB, V(0)->vA; QK(0); softmax(0)
#pragma unroll
  for (int b = 0; b < 4; ++b)
    kA[b] = *reinterpret_cast<const half8*>(kptr + b * 1024);
  kptr += KBLK * DP * 2;
#pragma unroll
  for (int b = 0; b < 4; ++b)
    kB[b] = *reinterpret_cast<const half8*>(kptr + b * 1024);
  kptr += KBLK * DP * 2;
#pragma unroll
  for (int ct = 0; ct < 3; ++ct) {
    vA[ct * 2 + 0] = *reinterpret_cast<const half8*>(vb[ct]);
    vA[ct * 2 + 1] = *reinterpret_cast<const half8*>(vb[ct] + 64);
    vb[ct] += KBLK * 2;
  }
  {
    f32x4 cvec = {coff, coff, coff, coff};
    f32x4 s[4];
#pragma unroll
    for (int b = 0; b < 4; ++b)
      s[b] = __builtin_amdgcn_mfma_f32_16x16x32_f16(kA[b], qfrag, cvec, 0, 0, 0);
    sm_write(s, 0);
  }
  asm volatile("s_waitcnt lgkmcnt(0)\n\ts_barrier" ::: "memory");

  // phase t: QK(t+1) from kq; rescale(t)+PV(t); loads K(t+2)->kd, V(t+1)->vd
  auto phase = [&](const half8(&kq)[4], const half8(&vp)[6], half8(&kd)[4],
                   half8(&vd)[6], int par, bool doK) {
    if (doK) {
#pragma unroll
      for (int b = 0; b < 4; ++b)
        kd[b] = *reinterpret_cast<const half8*>(kptr + b * 1024);
      kptr += KBLK * DP * 2;
    }
#pragma unroll
    for (int ct = 0; ct < 3; ++ct) {
      vd[ct * 2 + 0] = *reinterpret_cast<const half8*>(vb[ct]);
      vd[ct * 2 + 1] = *reinterpret_cast<const half8*>(vb[ct] + 64);
      vb[ct] += KBLK * 2;
    }

    f32x4 cvec = {coff, coff, coff, coff};
    f32x4 s[4];
#pragma unroll
    for (int b = 0; b < 4; ++b)
      s[b] = __builtin_amdgcn_mfma_f32_16x16x32_f16(kq[b], qfrag, cvec, 0, 0, 0);

    apply_rescale(par);
    pv(vp, par);

    sm_write(s, par ^ 1);
    asm volatile("s_waitcnt lgkmcnt(0)\n\ts_barrier" ::: "memory");
  };

  for (int t = 0; t < NTT - 2; t += 2) {
    phase(kB, vA, kA, vB, 0, true);
    phase(kA, vB, kB, vA, 1, true);
  }
  phase(kB, vA, kA, vB, 0, false);  // t = NTT-2

  // epilogue tile NTT-1 (par=1, NTT even)
  apply_rescale(1);
  pv(vB, 1);

  // row sums + coffs -> LDS (permuted)
  float sum = Lrow;
  sum += __shfl_xor(sum, 16);
  sum += __shfl_xor(sum, 32);
  if (lane < 16) {
    sm.Ls[li * 4 + wave] = sum;
    sm.Cs[li * 4 + wave] = coff;
  }
  __syncthreads();

  f32x4 Lv = *reinterpret_cast<const f32x4*>(&sm.Ls[li * 4]);
  f32x4 Cv = *reinterpret_cast<const f32x4*>(&sm.Cs[li * 4]);
  float osc[4];
  int eb[4];
#pragma unroll
  for (int qt = 0; qt < 4; ++qt) {
    eb[qt] = (int)(__float_as_uint(Lv[qt]) >> 23) - 127;        // floor(log2 L)
    osc[qt] = __uint_as_float((uint32_t)(127 - eb[qt]) << 23);  // 2^-e
  }
  half_t* ob = Op + (size_t)(n * 2 + z) * C * L;
#pragma unroll
  for (int ct = 0; ct < 3; ++ct)
#pragma unroll
    for (int qt = 0; qt < 4; ++qt)
#pragma unroll
      for (int r = 0; r < 4; ++r)
        ob[((size_t)(c0 + ct * 16 + 4 * g + r)) * L + q0 + qt * 16 + li] =
            (half_t)(acc[ct][qt][r] * osc[qt]);
  if (lane < 16) {
    size_t ridx = (size_t)(n * 2 + z) * L + q0 + wave * 16 + li;
    Lp[ridx] = Lv[wave] * osc[wave];
    // merge weight f = 2^(e - coff): acc_true = acc*2^-coff, O' = acc*2^-e
    Cp[ridx] = (float)eb[wave] - Cv[wave];
  }
}

// ---------------- split merge ----------------

__global__ __launch_bounds__(256) void merge_split(
    const half_t* __restrict__ Op, const float* __restrict__ Lp,
    const float* __restrict__ Cp, float* __restrict__ out) {
  int n = blockIdx.x;
  int l = blockIdx.y * 64 + (threadIdx.x & 63);
  int cs = threadIdx.x >> 6;

  size_t ra = (size_t)(n * 2 + 0) * L + l;
  size_t rb = (size_t)(n * 2 + 1) * L + l;
  float La = Lp[ra], Ca = Cp[ra];
  float Lb = Lp[rb], Cb = Cp[rb];
  float cm = fmaxf(Ca, Cb);
  float fa = exp2f(Ca - cm), fb = exp2f(Cb - cm);
  float D = La * fa + Lb * fb;
  float wa = fa / D, wb = fb / D;

  const half_t* Oa = Op + (size_t)(n * 2 + 0) * C * L;
  const half_t* Ob = Op + (size_t)(n * 2 + 1) * C * L;
  float* ob = out + (size_t)n * C * L;
#pragma unroll
  for (int j = 0; j < 48; ++j) {
    size_t idx = (size_t)(cs * 48 + j) * L + l;
    ob[idx] = wa * (float)Oa[idx] + wb * (float)Ob[idx];
  }
}

// ---------------- launcher ----------------

extern "C" void kernel_launch(void* const* d_in, const int* in_sizes, int n_in,
                              void* d_out, int out_size, void* d_ws, size_t ws_size,
                              hipStream_t stream) {
  (void)in_sizes; (void)n_in; (void)out_size; (void)ws_size;
  const float* x = (const float*)d_in[0];
  const float* Wq = (const float*)d_in[1];
  const float* Wk = (const float*)d_in[2];
  const float* Wv = (const float*)d_in[3];
  float* out = (float*)d_out;

  half_t* Qh = (half_t*)d_ws;                          // [NB][L][DP] f16
  half_t* Kh = Qh + (size_t)NB * L * DP;               // [NB][L][DP] f16
  half_t* Vh = Kh + (size_t)NB * L * DP;               // [NB][C][L]  f16
  half_t* Op = Vh + (size_t)NB * C * L;                // [NB][2][C][L] f16
  float* Lp = (float*)(Op + (size_t)NB * 2 * C * L);   // [NB][2][L] f32
  float* Cp = Lp + (size_t)NB * 2 * L;                 // [NB][2][L] f32

  hipLaunchKernelGGL(proj_mfma, dim3(NB * (L / BN)), dim3(256), 0, stream,
                     x, Wq, Wk, Wv, Qh, Kh, Vh);
  hipLaunchKernelGGL(attn_split, dim3(NB, L / QBLK, 2), dim3(256), 0, stream,
                     Qh, Kh, Vh, Op, Lp, Cp);
  hipLaunchKernelGGL(merge_split, dim3(NB, L / 64), dim3(256), 0, stream,
                     Op, Lp, Cp, out);
}

// Round 20
// 142.444 us; speedup vs baseline: 1.8195x; 1.0565x over previous
//
#include <hip/hip_runtime.h>
#include <hip/hip_bf16.h>

#define L 4096
#define NB 8
#define C 192
#define CQK 24
#define DP 32      // padded qk head dim
#define QBLK 64
#define KBLK 64
#define NT (L / KBLK)
// proj_mfma tile
#define BN 64      // l-columns per block
#define XS_W 200   // padded row width of Xs[l][c]
#define LOG2E 1.4426950408889634f

typedef _Float16 half_t;
typedef __fp16 fp16x2 __attribute__((ext_vector_type(2)));
typedef __fp16 fp16x4 __attribute__((ext_vector_type(4)));
typedef _Float16 half8 __attribute__((ext_vector_type(8)));
typedef float f32x4 __attribute__((ext_vector_type(4)));

// ---------------- MFMA projection kernel (unchanged) ----------------

__global__ __launch_bounds__(256, 2) void proj_mfma(const float* __restrict__ x,
                                                    const float* __restrict__ Wq,
                                                    const float* __restrict__ Wk,
                                                    const float* __restrict__ Wv,
                                                    half_t* __restrict__ Qh,
                                                    half_t* __restrict__ Kh,
                                                    half_t* __restrict__ Vh) {
  __shared__ half_t Xs[BN][XS_W];  // X^T tile [l][c]
  __shared__ half_t Qt[BN][DP];    // Q staging [l][o]
  __shared__ half_t Kt[BN][DP];    // K staging

  int tid = threadIdx.x;
  int lane = tid & 63;
  int wave = tid >> 6;
  int li = lane & 15;
  int g = lane >> 4;

  int blk = blockIdx.x;
  int n = blk >> 6;
  int l0 = (blk & 63) * BN;

  const float* xbase = x + (size_t)n * C * L + l0;
#pragma unroll
  for (int it = 0; it < 12; ++it) {
    int fid = it * 256 + tid;
    int l4 = fid & 15;
    int c = fid >> 4;
    f32x4 v = *reinterpret_cast<const f32x4*>(xbase + (size_t)c * L + l4 * 4);
#pragma unroll
    for (int j = 0; j < 4; ++j) Xs[l4 * 4 + j][c] = (half_t)v[j];
  }
  __syncthreads();

  const float* rowp[4];
  bool rvalid[4];
#pragma unroll
  for (int mt = 0; mt < 4; ++mt) {
    int row = wave * 64 + mt * 16 + li;
    const float* p;
    bool v = true;
    if (row < 32) {
      v = row < CQK;
      p = Wq + (size_t)(v ? row : 0) * C;
    } else if (row < 64) {
      v = (row - 32) < CQK;
      p = Wk + (size_t)(v ? row - 32 : 0) * C;
    } else {
      p = Wv + (size_t)(row - 64) * C;
    }
    rowp[mt] = p;
    rvalid[mt] = v;
  }

  f32x4 acc[4][4];
#pragma unroll
  for (int mt = 0; mt < 4; ++mt)
#pragma unroll
    for (int nt = 0; nt < 4; ++nt) acc[mt][nt] = {0.f, 0.f, 0.f, 0.f};

  half8 az;
#pragma unroll
  for (int j = 0; j < 8; ++j) az[j] = (half_t)0.f;

#pragma unroll
  for (int kk = 0; kk < 6; ++kk) {
    half8 af[4];
#pragma unroll
    for (int mt = 0; mt < 4; ++mt) {
      const float* p = rowp[mt] + kk * 32 + g * 8;
      f32x4 w0 = *reinterpret_cast<const f32x4*>(p);
      f32x4 w1 = *reinterpret_cast<const f32x4*>(p + 4);
      half8 a;
#pragma unroll
      for (int j = 0; j < 4; ++j) {
        a[j] = (half_t)w0[j];
        a[4 + j] = (half_t)w1[j];
      }
      af[mt] = rvalid[mt] ? a : az;
    }
#pragma unroll
    for (int nt = 0; nt < 4; ++nt) {
      half8 b = *reinterpret_cast<const half8*>(&Xs[nt * 16 + li][kk * 32 + g * 8]);
#pragma unroll
      for (int mt = 0; mt < 4; ++mt)
        acc[mt][nt] = __builtin_amdgcn_mfma_f32_16x16x32_f16(af[mt], b, acc[mt][nt], 0, 0, 0);
    }
  }

  if (wave >= 1) {
#pragma unroll
    for (int mt = 0; mt < 4; ++mt)
#pragma unroll
      for (int nt = 0; nt < 4; ++nt)
#pragma unroll
        for (int r = 0; r < 4; ++r) {
          int c = (wave - 1) * 64 + mt * 16 + 4 * g + r;
          int l = nt * 16 + li;
          Vh[((size_t)n * C + c) * L + l0 + l] = (half_t)acc[mt][nt][r];
        }
  } else {
#pragma unroll
    for (int mt = 0; mt < 4; ++mt)
#pragma unroll
      for (int nt = 0; nt < 4; ++nt)
#pragma unroll
        for (int r = 0; r < 4; ++r) {
          int o = (mt & 1) * 16 + 4 * g + r;
          int l = nt * 16 + li;
          if (mt < 2) Qt[l][o] = (half_t)(acc[mt][nt][r] * LOG2E);
          else        Kt[l][o] = (half_t)acc[mt][nt][r];
        }
  }
  __syncthreads();

  if (tid < 128) {
    int which = tid >> 6;
    int l = tid & 63;
    const half8* src = reinterpret_cast<const half8*>(which ? &Kt[l][0] : &Qt[l][0]);
    half_t* dstp = (which ? Kh : Qh) + ((size_t)n * L + l0 + l) * DP;
    half8* dst = reinterpret_cast<half8*>(dstp);
#pragma unroll
    for (int i = 0; i < 4; ++i) dst[i] = src[i];
  }
}

// ---------------- flash attention (single-pass, r12 structure) ----------------
// Round-20: split-KV reverted (r19 proved TLP-null: 2x blocks, identical
// 130 us and identical per-pipe utilization -> the per-tile wall is the
// phase-structure serial chain, not latency hideable by more waves; the
// merge kernel's ~12 us is pure overhead). Base = r12 (129 us attn, clean
// 104-VGPR codegen). One change: sm_write(t+1) moved BEFORE pv(t), so the
// P/rs ds_writes drain under PV's 24 MFMAs instead of stalling at the
// barrier's lgkmcnt(0) (saves the ~50-100 cy/tile barrier drain).

struct SMemA {
  half_t P[2][QBLK][KBLK];  // swizzled: byte ^= (row&7)<<4
  float rs[2][QBLK];        // per-row rescale, permuted [li*4+wave]
  float Ls[QBLK];           // row sums, permuted
};

__global__ __launch_bounds__(256, 2) void attn(const half_t* __restrict__ Qh,
                                               const half_t* __restrict__ Kh,
                                               const half_t* __restrict__ Vh,
                                               float* __restrict__ out) {
  __shared__ SMemA sm;

  const int tid = threadIdx.x;
  const int wave = tid >> 6;
  const int lane = tid & 63;
  const int li = lane & 15;
  const int g = lane >> 4;
  const int n = blockIdx.x;
  const int q0 = blockIdx.y * QBLK;
  const int c0 = wave * 48;
  const int swz = (li & 7) << 4;

  const half8 qfrag = *reinterpret_cast<const half8*>(
      Qh + ((size_t)(n * L + q0 + wave * 16 + li)) * DP + g * 8);

  const char* kptr = (const char*)(Kh + (size_t)n * L * DP) +
                     ((size_t)li * DP + g * 8) * 2;
  const char* vb[3];
  vb[0] = (const char*)(Vh + (size_t)n * C * L) +
          ((size_t)(c0 + li) * L + g * 8) * 2;
  vb[1] = vb[0] + (size_t)16 * L * 2;
  vb[2] = vb[0] + (size_t)32 * L * 2;

  f32x4 acc[3][4];
#pragma unroll
  for (int ct = 0; ct < 3; ++ct)
#pragma unroll
    for (int qt = 0; qt < 4; ++qt) acc[ct][qt] = {0.f, 0.f, 0.f, 0.f};

  float Lrow = 0.f;    // per-lane partial row sum (q = wave*16+li)
  float coff = -28.f;  // per-row offset (log2 units), in MFMA C-operand

  half8 kA[4], vA[6], kB[4], vB[6];

  // softmax + P/rs write for parity `par`
  auto sm_write = [&](const f32x4(&s)[4], int par) {
    float p[4][4];
    float mx = -1.0e30f;
#pragma unroll
    for (int b = 0; b < 4; ++b) {
      mx = fmaxf(mx, fmaxf(fmaxf(s[b][0], s[b][1]), fmaxf(s[b][2], s[b][3])));
#pragma unroll
      for (int r = 0; r < 4; ++r) p[b][r] = __builtin_amdgcn_exp2f(s[b][r]);
    }
    float sc = 1.0f;
    if (__any((int)(mx > 15.f))) {  // rare overflow path
      float m2 = fmaxf(mx, __shfl_xor(mx, 16));
      m2 = fmaxf(m2, __shfl_xor(m2, 32));
      if (m2 > 15.f) {
        sc = __builtin_amdgcn_exp2f(-m2);
        Lrow *= sc;
        coff -= m2;
#pragma unroll
        for (int b = 0; b < 4; ++b)
#pragma unroll
          for (int r = 0; r < 4; ++r)
            p[b][r] = __builtin_amdgcn_exp2f(s[b][r] - m2);
      }
    }
#pragma unroll
    for (int b = 0; b < 4; ++b)
#pragma unroll
      for (int r = 0; r < 4; ++r) Lrow += p[b][r];

    char* prow = (char*)&sm.P[par][wave * 16 + li][0];
#pragma unroll
    for (int b = 0; b < 4; ++b) {
      fp16x2 lo = __builtin_amdgcn_cvt_pkrtz(p[b][0], p[b][1]);
      fp16x2 hi = __builtin_amdgcn_cvt_pkrtz(p[b][2], p[b][3]);
      fp16x4 h = __builtin_shufflevector(lo, hi, 0, 1, 2, 3);
      *reinterpret_cast<fp16x4*>(prow + ((b * 32 + 8 * g) ^ swz)) = h;
    }
    if (lane < 16) sm.rs[par][li * 4 + wave] = sc;
  };

  auto apply_rescale = [&](int par) {
    f32x4 f = *reinterpret_cast<const f32x4*>(&sm.rs[par][li * 4]);
    bool an = (f[0] != 1.f) | (f[1] != 1.f) | (f[2] != 1.f) | (f[3] != 1.f);
    if (__any((int)an)) {
#pragma unroll
      for (int ct = 0; ct < 3; ++ct)
#pragma unroll
        for (int qt = 0; qt < 4; ++qt) acc[ct][qt] *= f[qt];
    }
  };

  auto pv = [&](const half8(&vp)[6], int par) {
#pragma unroll
    for (int ch = 0; ch < 2; ++ch)
#pragma unroll
      for (int qt = 0; qt < 4; ++qt) {
        const char* prow = (const char*)&sm.P[par][qt * 16 + li][0];
        half8 pfrag = *reinterpret_cast<const half8*>(
            prow + ((ch * 64 + 16 * g) ^ swz));
#pragma unroll
        for (int ct = 0; ct < 3; ++ct)
          acc[ct][qt] = __builtin_amdgcn_mfma_f32_16x16x32_f16(
              vp[ct * 2 + ch], pfrag, acc[ct][qt], 0, 0, 0);
      }
  };

  // prologue: K(0)->kA, K(1)->kB, V(0)->vA; QK(0); softmax(0)
#pragma unroll
  for (int b = 0; b < 4; ++b)
    kA[b] = *reinterpret_cast<const half8*>(kptr + b * 1024);
  kptr += KBLK * DP * 2;
#pragma unroll
  for (int b = 0; b < 4; ++b)
    kB[b] = *reinterpret_cast<const half8*>(kptr + b * 1024);
  kptr += KBLK * DP * 2;
#pragma unroll
  for (int ct = 0; ct < 3; ++ct) {
    vA[ct * 2 + 0] = *reinterpret_cast<const half8*>(vb[ct]);
    vA[ct * 2 + 1] = *reinterpret_cast<const half8*>(vb[ct] + 64);
    vb[ct] += KBLK * 2;
  }
  {
    f32x4 cvec = {coff, coff, coff, coff};
    f32x4 s[4];
#pragma unroll
    for (int b = 0; b < 4; ++b)
      s[b] = __builtin_amdgcn_mfma_f32_16x16x32_f16(kA[b], qfrag, cvec, 0, 0, 0);
    sm_write(s, 0);
  }
  asm volatile("s_waitcnt lgkmcnt(0)\n\ts_barrier" ::: "memory");

  // phase t: QK(t+1); rescale(t); softmax(t+1)->P[par^1] (writes drain under
  // PV); PV(t); loads K(t+2)->kd, V(t+1)->vd issued at top
  auto phase = [&](const half8(&kq)[4], const half8(&vp)[6], half8(&kd)[4],
                   half8(&vd)[6], int par, bool doK) {
    if (doK) {
#pragma unroll
      for (int b = 0; b < 4; ++b)
        kd[b] = *reinterpret_cast<const half8*>(kptr + b * 1024);
      kptr += KBLK * DP * 2;
    }
#pragma unroll
    for (int ct = 0; ct < 3; ++ct) {
      vd[ct * 2 + 0] = *reinterpret_cast<const half8*>(vb[ct]);
      vd[ct * 2 + 1] = *reinterpret_cast<const half8*>(vb[ct] + 64);
      vb[ct] += KBLK * 2;
    }

    f32x4 cvec = {coff, coff, coff, coff};
    f32x4 s[4];
#pragma unroll
    for (int b = 0; b < 4; ++b)
      s[b] = __builtin_amdgcn_mfma_f32_16x16x32_f16(kq[b], qfrag, cvec, 0, 0, 0);

    apply_rescale(par);
    sm_write(s, par ^ 1);  // softmax(t+1); ds_writes drain under pv's MFMAs
    pv(vp, par);

    asm volatile("s_waitcnt lgkmcnt(0)\n\ts_barrier" ::: "memory");
  };

  for (int t = 0; t < NT - 2; t += 2) {
    phase(kB, vA, kA, vB, 0, true);
    phase(kA, vB, kB, vA, 1, true);
  }
  phase(kB, vA, kA, vB, 0, false);  // t = NT-2

  // epilogue tile NT-1 (par=1)
  apply_rescale(1);
  pv(vB, 1);

  // row sums -> LDS (permuted) -> per-q inverse
  float sum = Lrow;
  sum += __shfl_xor(sum, 16);
  sum += __shfl_xor(sum, 32);
  if (lane < 16) sm.Ls[li * 4 + wave] = sum;
  __syncthreads();

  f32x4 Lv = *reinterpret_cast<const f32x4*>(&sm.Ls[li * 4]);
  float inv[4];
#pragma unroll
  for (int qt = 0; qt < 4; ++qt) inv[qt] = 1.0f / Lv[qt];

  // direct stores: c = c0+ct*16+4g+r, l = q0+qt*16+li (64B segments)
#pragma unroll
  for (int ct = 0; ct < 3; ++ct)
#pragma unroll
    for (int qt = 0; qt < 4; ++qt)
#pragma unroll
      for (int r = 0; r < 4; ++r)
        out[((size_t)n * C + c0 + ct * 16 + 4 * g + r) * L + q0 + qt * 16 + li] =
            acc[ct][qt][r] * inv[qt];
}

// ---------------- launcher ----------------

extern "C" void kernel_launch(void* const* d_in, const int* in_sizes, int n_in,
                              void* d_out, int out_size, void* d_ws, size_t ws_size,
                              hipStream_t stream) {
  (void)in_sizes; (void)n_in; (void)out_size; (void)ws_size;
  const float* x = (const float*)d_in[0];
  const float* Wq = (const float*)d_in[1];
  const float* Wk = (const float*)d_in[2];
  const float* Wv = (const float*)d_in[3];
  float* out = (float*)d_out;

  half_t* Qh = (half_t*)d_ws;                          // [NB][L][DP] f16
  half_t* Kh = Qh + (size_t)NB * L * DP;               // [NB][L][DP] f16
  half_t* Vh = Kh + (size_t)NB * L * DP;               // [NB][C][L]  f16

  hipLaunchKernelGGL(proj_mfma, dim3(NB * (L / BN)), dim3(256), 0, stream,
                     x, Wq, Wk, Wv, Qh, Kh, Vh);
  hipLaunchKernelGGL(attn, dim3(NB, L / QBLK), dim3(256), 0, stream,
                     Qh, Kh, Vh, out);
}